// Round 10
// baseline (88.252 us; speedup 1.0000x reference)
//
#include <hip/hip_runtime.h>
#include <hip/hip_bf16.h>

typedef short short8 __attribute__((ext_vector_type(8)));
typedef float f32x16 __attribute__((ext_vector_type(16)));

#define ND 128
#define LD 128
#define EE 128
#define NQ 128
#define LQ 32
#define STRIDE 136     // bf16 elems/row: 272B = 17*16B, b128-aligned, breaks pow2
#define HROWS 64       // rows per half-tile (pipeline stage)
#define HELEMS (HROWS * EE)   // 8192 elems per half

// ---- Kernel 1: merged convert (from R4, proven).
// blocks [0, 2048): doc fp32 -> bf16 copy-cast (1 float4/thread)
// blocks [2048, 2176): query fp32 [E][Lq] -> bf16 [Lq][E] via LDS transpose ----
__global__ __launch_bounds__(256)
void convert_kernel(const float* __restrict__ doc, const float* __restrict__ qry,
                    __hip_bfloat16* __restrict__ docB, __hip_bfloat16* __restrict__ qB) {
  const int tid = threadIdx.x;
  if (blockIdx.x < 2048) {
    int gid = blockIdx.x * 256 + tid;        // 524288 float4 chunks of doc
    float4 v = reinterpret_cast<const float4*>(doc)[gid];
    union { ushort4 u; __hip_bfloat16 b[4]; } o;
    o.b[0] = __float2bfloat16(v.x);
    o.b[1] = __float2bfloat16(v.y);
    o.b[2] = __float2bfloat16(v.z);
    o.b[3] = __float2bfloat16(v.w);
    reinterpret_cast<ushort4*>(docB)[gid] = o.u;
    return;
  }
  __shared__ float s[LQ][EE + 1];            // 32 x 129 fp32
  const int q = blockIdx.x - 2048;
  const float* src = qry + q * (EE * LQ);
  #pragma unroll
  for (int i = 0; i < 4; ++i) {              // coalesced float4 read of [E][L]
    int c = i * 256 + tid;
    int e = c >> 3;
    int l = (c & 7) << 2;
    float4 v = reinterpret_cast<const float4*>(src)[c];
    s[l + 0][e] = v.x;
    s[l + 1][e] = v.y;
    s[l + 2][e] = v.z;
    s[l + 3][e] = v.w;
  }
  __syncthreads();
  __hip_bfloat16* dst = qB + q * (LQ * EE);
  #pragma unroll
  for (int i = 0; i < 4; ++i) {              // coalesced ushort4 write of [L][E]
    int c = i * 256 + tid;
    int l = c >> 5;
    int e = (c & 31) << 2;
    union { ushort4 u; __hip_bfloat16 b[4]; } o;
    o.b[0] = __float2bfloat16(s[l][e + 0]);
    o.b[1] = __float2bfloat16(s[l][e + 1]);
    o.b[2] = __float2bfloat16(s[l][e + 2]);
    o.b[3] = __float2bfloat16(s[l][e + 3]);
    reinterpret_cast<ushort4*>(dst)[c] = o.u;
  }
}

// ---- Kernel 2: fused maxsim, 32x32x16 MFMA, query-resident, 4-segment
// pipeline — R8 structure, but staging bf16 from docB (no cvt in hot loop)
// with only 8 staging regs in flight. Block = 256 thr = (2 docs x 2 halves,
// 8 queries). Grid 64x16 = 1024 = 4 blocks/CU (LDS 2*17408*4 = 139KB).
// Reg demand ~118 <= 128 -> 4 waves/SIMD WITHOUT forcing. NO min-waves
// bound: R2/R7 proved forcing the 128 budget spills bfrag (~90MB scratch). ----
__global__ __launch_bounds__(256)
void maxsim_kernel(const __hip_bfloat16* __restrict__ docB,
                   const __hip_bfloat16* __restrict__ qB,
                   float* __restrict__ out) {
  __shared__ __hip_bfloat16 sdoc[2][HROWS * STRIDE];
  const int d0   = blockIdx.x * 2;
  const int qblk = blockIdx.y;
  const int tid  = threadIdx.x;
  const int wave = tid >> 6;
  const int lane = tid & 63;
  const int ln31 = lane & 31;        // m (A rows) / n (B cols = query token l)
  const int kh   = lane >> 5;        // k-group: k = kh*8 + j
  const int q0   = qblk * 8 + wave * 2;

  // B-frags, 32x32x16 layout: B[n=lane&31][k=ks*16+kh*8+j]. 2 queries x 8 ks
  // = 64 VGPRs, loaded ONCE from qB and held for the whole kernel.
  short8 bfrag[2][8];
  #pragma unroll
  for (int qq = 0; qq < 2; ++qq) {
    const __hip_bfloat16* qp = qB + (q0 + qq) * (LQ * EE) + ln31 * EE + kh * 8;
    #pragma unroll
    for (int ks = 0; ks < 8; ++ks)
      bfrag[qq][ks] = *reinterpret_cast<const short8*>(qp + ks * 16);
  }

  uint4 pf[2];                       // staging in-flight regs (8 VGPRs)
  float colmax0 = -3.0e38f, colmax1 = -3.0e38f;

  // Segment seg: doc d0+(seg>>1), rows (seg&1)*64..+63 = 1024 uint4 chunks of
  // bf16 (16 chunks per 128-elem row). Group grp covers chunks c = grp*512 +
  // i*256 + tid, i=0..1 (2 uint4 in flight).
  auto issue = [&](int seg, int grp) {
    const uint4* src = reinterpret_cast<const uint4*>(
        docB + (d0 + (seg >> 1)) * (LD * EE) + (seg & 1) * HELEMS);
    #pragma unroll
    for (int i = 0; i < 2; ++i)
      pf[i] = src[grp * 512 + i * 256 + tid];
  };
  auto flush = [&](int seg, int grp) {
    __hip_bfloat16* dst = sdoc[seg & 1];
    #pragma unroll
    for (int i = 0; i < 2; ++i) {
      int c = grp * 512 + i * 256 + tid;
      *reinterpret_cast<uint4*>(&dst[(c >> 4) * STRIDE + ((c & 15) << 3)]) = pf[i];
    }
  };
  // One 32-row m-tile of segment seg: 8 ks x 2 MFMA, fold rows into colmax.
  auto compute_mt = [&](int seg, int mt) {
    const __hip_bfloat16* sp = sdoc[seg & 1];
    f32x16 acc0 = {0.f, 0.f, 0.f, 0.f, 0.f, 0.f, 0.f, 0.f,
                   0.f, 0.f, 0.f, 0.f, 0.f, 0.f, 0.f, 0.f};
    f32x16 acc1 = acc0;
    #pragma unroll
    for (int ks = 0; ks < 8; ++ks) {
      short8 a = *reinterpret_cast<const short8*>(
          &sp[(mt * 32 + ln31) * STRIDE + ks * 16 + kh * 8]);
      acc0 = __builtin_amdgcn_mfma_f32_32x32x16_bf16(a, bfrag[0][ks], acc0, 0, 0, 0);
      acc1 = __builtin_amdgcn_mfma_f32_32x32x16_bf16(a, bfrag[1][ks], acc1, 0, 0, 0);
    }
    float t0 = fmaxf(fmaxf(fmaxf(acc0[0], acc0[1]), fmaxf(acc0[2], acc0[3])),
                     fmaxf(fmaxf(acc0[4], acc0[5]), fmaxf(acc0[6], acc0[7])));
    float u0 = fmaxf(fmaxf(fmaxf(acc0[8], acc0[9]), fmaxf(acc0[10], acc0[11])),
                     fmaxf(fmaxf(acc0[12], acc0[13]), fmaxf(acc0[14], acc0[15])));
    colmax0 = fmaxf(colmax0, fmaxf(t0, u0));
    float t1 = fmaxf(fmaxf(fmaxf(acc1[0], acc1[1]), fmaxf(acc1[2], acc1[3])),
                     fmaxf(fmaxf(acc1[4], acc1[5]), fmaxf(acc1[6], acc1[7])));
    float u1 = fmaxf(fmaxf(fmaxf(acc1[8], acc1[9]), fmaxf(acc1[10], acc1[11])),
                     fmaxf(fmaxf(acc1[12], acc1[13]), fmaxf(acc1[14], acc1[15])));
    colmax1 = fmaxf(colmax1, fmaxf(t1, u1));
  };

  // Prologue: stage segment 0 fully into sdoc[0].
  issue(0, 0); flush(0, 0);
  issue(0, 1); flush(0, 1);
  __syncthreads();

  // Pipeline: compute seg from sdoc[seg&1] while staging seg+1 to the other
  // buffer. The buffer seg+1 targets was last read in seg-1 (barrier-protected).
  #pragma unroll
  for (int seg = 0; seg < 4; ++seg) {
    if (seg < 3) issue(seg + 1, 0);
    compute_mt(seg, 0);
    if (seg < 3) { flush(seg + 1, 0); issue(seg + 1, 1); }
    compute_mt(seg, 1);
    if (seg < 3) flush(seg + 1, 1);

    if (seg & 1) {
      // Doc d0 + (seg>>1) done. C/D rows r=(reg&3)+8*(reg>>2)+4*kh already
      // folded; xor32 merges kh halves -> per-col max over 128 tokens; sum
      // 32 cols via xor 1/2/4/8/16.
      const int d = d0 + (seg >> 1);
      float m = fmaxf(colmax0, __shfl_xor(colmax0, 32, 64));
      float s = m;
      s += __shfl_xor(s, 1, 64);
      s += __shfl_xor(s, 2, 64);
      s += __shfl_xor(s, 4, 64);
      s += __shfl_xor(s, 8, 64);
      s += __shfl_xor(s, 16, 64);
      if (lane == 0) out[q0 * ND + d] = s;
      float m1 = fmaxf(colmax1, __shfl_xor(colmax1, 32, 64));
      float s1 = m1;
      s1 += __shfl_xor(s1, 1, 64);
      s1 += __shfl_xor(s1, 2, 64);
      s1 += __shfl_xor(s1, 4, 64);
      s1 += __shfl_xor(s1, 8, 64);
      s1 += __shfl_xor(s1, 16, 64);
      if (lane == 0) out[(q0 + 1) * ND + d] = s1;
      colmax0 = -3.0e38f;
      colmax1 = -3.0e38f;
    }
    __syncthreads();
  }
}

extern "C" void kernel_launch(void* const* d_in, const int* in_sizes, int n_in,
                              void* d_out, int out_size, void* d_ws, size_t ws_size,
                              hipStream_t stream) {
  const float* doc = (const float*)d_in[0];   // [128,128,128] fp32
  const float* qry = (const float*)d_in[1];   // [128,128,32]  fp32
  float* out = (float*)d_out;                 // [128,128]     fp32

  __hip_bfloat16* docB = (__hip_bfloat16*)d_ws;            // 4 MiB
  __hip_bfloat16* qB   = docB + ND * LD * EE;              // 1 MiB

  convert_kernel<<<dim3(2048 + NQ), dim3(256), 0, stream>>>(doc, qry, docB, qB);
  maxsim_kernel<<<dim3(ND / 2, NQ / 8), dim3(256), 0, stream>>>(docB, qB, out);
}

// Round 11
// 83.547 us; speedup vs baseline: 1.0563x; 1.0563x over previous
//
#include <hip/hip_runtime.h>
#include <hip/hip_bf16.h>

typedef short short8 __attribute__((ext_vector_type(8)));
typedef float f32x16 __attribute__((ext_vector_type(16)));

#define ND 128
#define LD 128
#define EE 128
#define NQ 128
#define LQ 32
#define DSTRIDE 136   // bf16/row in convert LDS: 272B = 17*16B

// ---- Kernel 1: convert to MFMA-fragment-ordered bf16.
// blocks [0,128): doc d -> docA, chunk ((d*4+mt)*8+ks)*64+lane holds
//   bf16(doc[d][mt*32+(lane&31)][ks*16+(lane>>5)*8 + 0..7])   (A-frag order)
// blocks [128,256): query q -> qB2, chunk (q*8+ks)*64+lane holds
//   bf16(qry[q][ks*16+(lane>>5)*8 + 0..7][lane&31])           (B-frag order)
__global__ __launch_bounds__(256)
void convert_kernel(const float* __restrict__ doc, const float* __restrict__ qry,
                    __hip_bfloat16* __restrict__ docA, __hip_bfloat16* __restrict__ qB2) {
  const int tid = threadIdx.x;
  if (blockIdx.x < 128) {
    const int d = blockIdx.x;
    __shared__ __hip_bfloat16 s[LD * DSTRIDE];   // 34 KB
    const float4* src = reinterpret_cast<const float4*>(doc + d * LD * EE);
    #pragma unroll
    for (int i = 0; i < 16; ++i) {               // 4096 float4, coalesced
      int c = i * 256 + tid;
      int t = c >> 5;
      int e = (c & 31) << 2;
      float4 v = src[c];
      union { ushort4 u; __hip_bfloat16 b[4]; } o;
      o.b[0] = __float2bfloat16(v.x);
      o.b[1] = __float2bfloat16(v.y);
      o.b[2] = __float2bfloat16(v.z);
      o.b[3] = __float2bfloat16(v.w);
      *reinterpret_cast<ushort4*>(&s[t * DSTRIDE + e]) = o.u;
    }
    __syncthreads();
    uint4* dst = reinterpret_cast<uint4*>(docA + d * LD * EE);
    #pragma unroll
    for (int i = 0; i < 8; ++i) {                // 2048 fragment chunks, coalesced out
      int cc = i * 256 + tid;
      int mt = cc >> 9;
      int ks = (cc >> 6) & 7;
      int lo = cc & 63;
      int t  = mt * 32 + (lo & 31);
      int e0 = ks * 16 + (lo >> 5) * 8;
      dst[cc] = *reinterpret_cast<const uint4*>(&s[t * DSTRIDE + e0]);
    }
    return;
  }
  const int q = blockIdx.x - 128;
  __shared__ float sq[EE][LQ + 1];               // 16.9 KB, pad breaks banks
  const float* src = qry + q * EE * LQ;
  #pragma unroll
  for (int i = 0; i < 4; ++i) {                  // 1024 float4, coalesced
    int c = i * 256 + tid;
    int e = c >> 3;
    int l = (c & 7) << 2;
    float4 v = reinterpret_cast<const float4*>(src)[c];
    sq[e][l + 0] = v.x;
    sq[e][l + 1] = v.y;
    sq[e][l + 2] = v.z;
    sq[e][l + 3] = v.w;
  }
  __syncthreads();
  uint4* dst = reinterpret_cast<uint4*>(qB2 + q * LQ * EE);
  #pragma unroll
  for (int i = 0; i < 2; ++i) {                  // 512 fragment chunks, coalesced out
    int cc = i * 256 + tid;
    int ks = cc >> 6;
    int lo = cc & 63;
    int l  = lo & 31;
    int e0 = ks * 16 + (lo >> 5) * 8;
    union { uint4 u; __hip_bfloat16 b[8]; } o;
    #pragma unroll
    for (int j = 0; j < 8; ++j)
      o.b[j] = __float2bfloat16(sq[e0 + j][l]);
    dst[cc] = o.u;
  }
}

// ---- Kernel 2: maxsim, doc-in-registers. Block = (1 doc, 32 queries),
// grid 128x4 = 512 = 2 blocks/CU (LDS 16KB; VGPR ~212 <= 256 via (256,2) —
// NOT the spill-prone 128 budget of R2/R7). Wave w holds m-tile w's A-frags
// (32 VGPRs) permanently; streams query pairs with double-buffered coalesced
// B loads; 16 MFMAs/pair as 2 interleaved chains; per query: fold + xor32 +
// one predicated ds_write of the 32 col-maxes. ZERO barriers in main loop;
// one barrier + small LDS reduce (max over 4 waves, sum 32 cols) at end. ----
__global__ __launch_bounds__(256, 2)
void maxsim_kernel(const __hip_bfloat16* __restrict__ docA,
                   const __hip_bfloat16* __restrict__ qB2,
                   float* __restrict__ out) {
  __shared__ float pmax[32][4][32];   // [q][wave][col] = 16 KB
  const int d    = blockIdx.x;
  const int qg   = blockIdx.y;
  const int tid  = threadIdx.x;
  const int wave = tid >> 6;
  const int lane = tid & 63;
  const int q0   = qg * 32;

  // A-frags: 8 coalesced b128 loads, held for whole kernel.
  const short8* As = reinterpret_cast<const short8*>(docA)
                   + (d * 4 + wave) * 512 + lane;
  short8 afrag[8];
  #pragma unroll
  for (int ks = 0; ks < 8; ++ks) afrag[ks] = As[ks * 64];

  const short8* Bs = reinterpret_cast<const short8*>(qB2) + q0 * 512 + lane;

  short8 b[2][2][8];                  // [buf][query-in-pair][ks] = 128 VGPRs
  #pragma unroll
  for (int ks = 0; ks < 8; ++ks) {
    b[0][0][ks] = Bs[ks * 64];
    b[0][1][ks] = Bs[(8 + ks) * 64];
  }

  #pragma unroll 2
  for (int p = 0; p < 16; ++p) {
    const int cur = p & 1, nxt = cur ^ 1;
    if (p < 15) {                     // prefetch next pair's B-frags
      const short8* Bn = Bs + (2 * p + 2) * 512;
      #pragma unroll
      for (int ks = 0; ks < 8; ++ks) {
        b[nxt][0][ks] = Bn[ks * 64];
        b[nxt][1][ks] = Bn[(8 + ks) * 64];
      }
    }
    f32x16 a0 = {0.f, 0.f, 0.f, 0.f, 0.f, 0.f, 0.f, 0.f,
                 0.f, 0.f, 0.f, 0.f, 0.f, 0.f, 0.f, 0.f};
    f32x16 a1 = a0;
    #pragma unroll
    for (int ks = 0; ks < 8; ++ks) {  // 2 interleaved dep chains
      a0 = __builtin_amdgcn_mfma_f32_32x32x16_bf16(afrag[ks], b[cur][0][ks], a0, 0, 0, 0);
      a1 = __builtin_amdgcn_mfma_f32_32x32x16_bf16(afrag[ks], b[cur][1][ks], a1, 0, 0, 0);
    }
    // Fold 16 acc rows (r=(reg&3)+8*(reg>>2)+4*kh) -> max; xor32 merges kh
    // halves so every lane holds max over this wave's 32 rows for col lane&31.
    float m0 = fmaxf(
        fmaxf(fmaxf(fmaxf(a0[0], a0[1]), fmaxf(a0[2], a0[3])),
              fmaxf(fmaxf(a0[4], a0[5]), fmaxf(a0[6], a0[7]))),
        fmaxf(fmaxf(fmaxf(a0[8], a0[9]), fmaxf(a0[10], a0[11])),
              fmaxf(fmaxf(a0[12], a0[13]), fmaxf(a0[14], a0[15]))));
    float m1 = fmaxf(
        fmaxf(fmaxf(fmaxf(a1[0], a1[1]), fmaxf(a1[2], a1[3])),
              fmaxf(fmaxf(a1[4], a1[5]), fmaxf(a1[6], a1[7]))),
        fmaxf(fmaxf(fmaxf(a1[8], a1[9]), fmaxf(a1[10], a1[11])),
              fmaxf(fmaxf(a1[12], a1[13]), fmaxf(a1[14], a1[15]))));
    m0 = fmaxf(m0, __shfl_xor(m0, 32, 64));
    m1 = fmaxf(m1, __shfl_xor(m1, 32, 64));
    if (lane < 32) {
      pmax[2 * p    ][wave][lane] = m0;
      pmax[2 * p + 1][wave][lane] = m1;
    }
  }
  __syncthreads();

  // Reduce: thread t -> query q=t>>3, cols (t&7)*4 .. +3. Max over 4 waves,
  // partial col-sum, then xor 1/2/4 combines the 8 threads of each query.
  {
    int q  = tid >> 3;
    int c0 = (tid & 7) * 4;
    float ssum = 0.f;
    #pragma unroll
    for (int i = 0; i < 4; ++i) {
      int c = c0 + i;
      ssum += fmaxf(fmaxf(pmax[q][0][c], pmax[q][1][c]),
                    fmaxf(pmax[q][2][c], pmax[q][3][c]));
    }
    ssum += __shfl_xor(ssum, 1, 64);
    ssum += __shfl_xor(ssum, 2, 64);
    ssum += __shfl_xor(ssum, 4, 64);
    if ((tid & 7) == 0) out[(q0 + q) * ND + d] = ssum;
  }
}

extern "C" void kernel_launch(void* const* d_in, const int* in_sizes, int n_in,
                              void* d_out, int out_size, void* d_ws, size_t ws_size,
                              hipStream_t stream) {
  const float* doc = (const float*)d_in[0];   // [128,128,128] fp32
  const float* qry = (const float*)d_in[1];   // [128,128,32]  fp32
  float* out = (float*)d_out;                 // [128,128]     fp32

  __hip_bfloat16* docA = (__hip_bfloat16*)d_ws;            // 4 MiB, frag-ordered
  __hip_bfloat16* qB2  = docA + ND * LD * EE;              // 1 MiB, frag-ordered

  convert_kernel<<<dim3(256), dim3(256), 0, stream>>>(doc, qry, docA, qB2);
  maxsim_kernel<<<dim3(ND, NQ / 32), dim3(256), 0, stream>>>(docA, qB2, out);
}

// Round 12
// 77.221 us; speedup vs baseline: 1.1428x; 1.0819x over previous
//
#include <hip/hip_runtime.h>
#include <hip/hip_bf16.h>

typedef short short8 __attribute__((ext_vector_type(8)));
typedef float f32x16 __attribute__((ext_vector_type(16)));

#define ND 128
#define LD 128
#define EE 128
#define NQ 128
#define LQ 32
#define DSTRIDE 136   // bf16/row in convert LDS: 272B = 17*16B

// ---- Kernel 1: convert to MFMA-fragment-ordered bf16 (proven in R11).
// blocks [0,128): doc d -> docA, chunk ((d*4+mt)*8+ks)*64+lane holds
//   bf16(doc[d][mt*32+(lane&31)][ks*16+(lane>>5)*8 + 0..7])   (A-frag order)
// blocks [128,256): query q -> qB2, chunk (q*8+ks)*64+lane holds
//   bf16(qry[q][ks*16+(lane>>5)*8 + 0..7][lane&31])           (B-frag order)
__global__ __launch_bounds__(256)
void convert_kernel(const float* __restrict__ doc, const float* __restrict__ qry,
                    __hip_bfloat16* __restrict__ docA, __hip_bfloat16* __restrict__ qB2) {
  const int tid = threadIdx.x;
  if (blockIdx.x < 128) {
    const int d = blockIdx.x;
    __shared__ __hip_bfloat16 s[LD * DSTRIDE];   // 34 KB
    const float4* src = reinterpret_cast<const float4*>(doc + d * LD * EE);
    #pragma unroll
    for (int i = 0; i < 16; ++i) {               // 4096 float4, coalesced
      int c = i * 256 + tid;
      int t = c >> 5;
      int e = (c & 31) << 2;
      float4 v = src[c];
      union { ushort4 u; __hip_bfloat16 b[4]; } o;
      o.b[0] = __float2bfloat16(v.x);
      o.b[1] = __float2bfloat16(v.y);
      o.b[2] = __float2bfloat16(v.z);
      o.b[3] = __float2bfloat16(v.w);
      *reinterpret_cast<ushort4*>(&s[t * DSTRIDE + e]) = o.u;
    }
    __syncthreads();
    uint4* dst = reinterpret_cast<uint4*>(docA + d * LD * EE);
    #pragma unroll
    for (int i = 0; i < 8; ++i) {                // 2048 fragment chunks, coalesced
      int cc = i * 256 + tid;
      int mt = cc >> 9;
      int ks = (cc >> 6) & 7;
      int lo = cc & 63;
      int t  = mt * 32 + (lo & 31);
      int e0 = ks * 16 + (lo >> 5) * 8;
      dst[cc] = *reinterpret_cast<const uint4*>(&s[t * DSTRIDE + e0]);
    }
    return;
  }
  const int q = blockIdx.x - 128;
  __shared__ float sq[EE][LQ + 1];               // 16.9 KB, pad breaks banks
  const float* src = qry + q * EE * LQ;
  #pragma unroll
  for (int i = 0; i < 4; ++i) {                  // 1024 float4, coalesced
    int c = i * 256 + tid;
    int e = c >> 3;
    int l = (c & 7) << 2;
    float4 v = reinterpret_cast<const float4*>(src)[c];
    sq[e][l + 0] = v.x;
    sq[e][l + 1] = v.y;
    sq[e][l + 2] = v.z;
    sq[e][l + 3] = v.w;
  }
  __syncthreads();
  uint4* dst = reinterpret_cast<uint4*>(qB2 + q * LQ * EE);
  #pragma unroll
  for (int i = 0; i < 2; ++i) {                  // 512 fragment chunks, coalesced
    int cc = i * 256 + tid;
    int ks = cc >> 6;
    int lo = cc & 63;
    int l  = lo & 31;
    int e0 = ks * 16 + (lo >> 5) * 8;
    union { uint4 u; __hip_bfloat16 b[8]; } o;
    #pragma unroll
    for (int j = 0; j < 8; ++j)
      o.b[j] = __float2bfloat16(sq[e0 + j][l]);
    dst[cc] = o.u;
  }
}

// ---- Kernel 2: maxsim, FULL doc per wave, zero LDS, zero barriers.
// Block = 256 thr = 4 waves; wave holds doc d entirely in A-frags (128 VGPRs)
// and owns 8 DISTINCT queries (4 pairs, single-buffered B = 64 VGPRs, pair
// loop unroll 1 so regs are reused). No intra-block load redundancy: per-CU
// L2 traffic ~768 KB (vs R11's 2.25 MB — its real limiter). Per pair: 64
// MFMAs as 2 interleaved chains; reduction fully in-register (fold 16 regs ->
// xor32 merges kh halves -> col-sum xor 1/2/4/8/16 -> 1 store/query).
// Grid (128 d, 4 qg) = 512 blocks = exactly 2 blocks/CU at 2 waves/SIMD
// (VGPR ~236 <= 256; NO min-waves forcing — R2/R7 spill lesson). ----
__global__ __launch_bounds__(256)
void maxsim_kernel(const __hip_bfloat16* __restrict__ docA,
                   const __hip_bfloat16* __restrict__ qB2,
                   float* __restrict__ out) {
  const int d    = blockIdx.x;
  const int qg   = blockIdx.y;
  const int tid  = threadIdx.x;
  const int wave = tid >> 6;
  const int lane = tid & 63;
  const int q0   = qg * 32 + wave * 8;     // this wave's 8 queries

  // A-frags: whole doc, 32 coalesced b128 loads, held for the whole kernel.
  const short8* As = reinterpret_cast<const short8*>(docA) + d * 2048 + lane;
  short8 afrag[4][8];
  #pragma unroll
  for (int mt = 0; mt < 4; ++mt)
    #pragma unroll
    for (int ks = 0; ks < 8; ++ks)
      afrag[mt][ks] = As[(mt * 8 + ks) * 64];

  const short8* Bs = reinterpret_cast<const short8*>(qB2) + q0 * 512 + lane;

  #pragma unroll 1
  for (int p = 0; p < 4; ++p) {
    // B-frags for this query pair: 16 coalesced b128 loads (64 VGPRs, reused).
    const short8* Bp = Bs + p * 1024;
    short8 b0[8], b1[8];
    #pragma unroll
    for (int ks = 0; ks < 8; ++ks) {
      b0[ks] = Bp[ks * 64];
      b1[ks] = Bp[(8 + ks) * 64];
    }

    float cm0 = -3.0e38f, cm1 = -3.0e38f;
    #pragma unroll
    for (int mt = 0; mt < 4; ++mt) {
      f32x16 a0 = {0.f, 0.f, 0.f, 0.f, 0.f, 0.f, 0.f, 0.f,
                   0.f, 0.f, 0.f, 0.f, 0.f, 0.f, 0.f, 0.f};
      f32x16 a1 = a0;
      #pragma unroll
      for (int ks = 0; ks < 8; ++ks) {     // 2 interleaved dep chains
        a0 = __builtin_amdgcn_mfma_f32_32x32x16_bf16(afrag[mt][ks], b0[ks], a0, 0, 0, 0);
        a1 = __builtin_amdgcn_mfma_f32_32x32x16_bf16(afrag[mt][ks], b1[ks], a1, 0, 0, 0);
      }
      // Fold 16 acc rows (r=(reg&3)+8*(reg>>2)+4*kh) into running col-max.
      float m0 = fmaxf(
          fmaxf(fmaxf(fmaxf(a0[0], a0[1]), fmaxf(a0[2], a0[3])),
                fmaxf(fmaxf(a0[4], a0[5]), fmaxf(a0[6], a0[7]))),
          fmaxf(fmaxf(fmaxf(a0[8], a0[9]), fmaxf(a0[10], a0[11])),
                fmaxf(fmaxf(a0[12], a0[13]), fmaxf(a0[14], a0[15]))));
      cm0 = fmaxf(cm0, m0);
      float m1 = fmaxf(
          fmaxf(fmaxf(fmaxf(a1[0], a1[1]), fmaxf(a1[2], a1[3])),
                fmaxf(fmaxf(a1[4], a1[5]), fmaxf(a1[6], a1[7]))),
          fmaxf(fmaxf(fmaxf(a1[8], a1[9]), fmaxf(a1[10], a1[11])),
                fmaxf(fmaxf(a1[12], a1[13]), fmaxf(a1[14], a1[15]))));
      cm1 = fmaxf(cm1, m1);
    }

    // xor32 merges the kh halves: every lane now has max over all 128 doc
    // tokens for col lane&31; sum the 32 cols; lane 0 stores.
    cm0 = fmaxf(cm0, __shfl_xor(cm0, 32, 64));
    cm1 = fmaxf(cm1, __shfl_xor(cm1, 32, 64));
    float s0 = cm0, s1 = cm1;
    s0 += __shfl_xor(s0, 1, 64);
    s0 += __shfl_xor(s0, 2, 64);
    s0 += __shfl_xor(s0, 4, 64);
    s0 += __shfl_xor(s0, 8, 64);
    s0 += __shfl_xor(s0, 16, 64);
    s1 += __shfl_xor(s1, 1, 64);
    s1 += __shfl_xor(s1, 2, 64);
    s1 += __shfl_xor(s1, 4, 64);
    s1 += __shfl_xor(s1, 8, 64);
    s1 += __shfl_xor(s1, 16, 64);
    if (lane == 0) {
      out[(q0 + 2 * p) * ND + d]     = s0;
      out[(q0 + 2 * p + 1) * ND + d] = s1;
    }
  }
}

extern "C" void kernel_launch(void* const* d_in, const int* in_sizes, int n_in,
                              void* d_out, int out_size, void* d_ws, size_t ws_size,
                              hipStream_t stream) {
  const float* doc = (const float*)d_in[0];   // [128,128,128] fp32
  const float* qry = (const float*)d_in[1];   // [128,128,32]  fp32
  float* out = (float*)d_out;                 // [128,128]     fp32

  __hip_bfloat16* docA = (__hip_bfloat16*)d_ws;            // 4 MiB, frag-ordered
  __hip_bfloat16* qB2  = docA + ND * LD * EE;              // 1 MiB, frag-ordered

  convert_kernel<<<dim3(256), dim3(256), 0, stream>>>(doc, qry, docA, qB2);
  maxsim_kernel<<<dim3(ND, NQ / 32), dim3(256), 0, stream>>>(docA, qB2, out);
}

// Round 13
// 70.605 us; speedup vs baseline: 1.2499x; 1.0937x over previous
//
#include <hip/hip_runtime.h>
#include <hip/hip_bf16.h>

typedef int int4v  __attribute__((ext_vector_type(4)));
typedef int i32x16 __attribute__((ext_vector_type(16)));

#define ND 128
#define LD 128
#define EE 128
#define NQ 128
#define LQ 32

__device__ __forceinline__ unsigned q8u(float x) {
  float v = __builtin_rintf(x * 127.0f);          // inputs are L2-normalized: |x|<=1
  v = fminf(127.0f, fmaxf(-127.0f, v));
  return ((int)v) & 0xff;
}
__device__ __forceinline__ int imax(int a, int b) { return a > b ? a : b; }

// ---- Kernel 1: convert fp32 -> fragment-ordered i8 (fixed scale 127).
// blocks [0,128): doc d -> docA8. Chunk ((d*4+mt)*4+ks)*64+lane (16B) holds
//   i8(doc[d][mt*32+(lane&31)][ks*32+(lane>>5)*16 + 0..15])   (A-frag, K=32)
// blocks [128,256): query q -> qB8. Chunk (q*4+ks)*64+lane holds
//   i8(qry[q][ks*32+(lane>>5)*16 + 0..15][lane&31])           (B-frag, K=32)
__global__ __launch_bounds__(256)
void convert_kernel(const float* __restrict__ doc, const float* __restrict__ qry,
                    unsigned char* __restrict__ docA8, unsigned char* __restrict__ qB8) {
  const int tid = threadIdx.x;
  if (blockIdx.x < 128) {
    const int d = blockIdx.x;
    __shared__ unsigned char s8[LD * 144];   // 18 KB; row stride 144B = 9*16 (b128-aligned)
    const float4* src = reinterpret_cast<const float4*>(doc + d * LD * EE);
    #pragma unroll
    for (int i = 0; i < 16; ++i) {           // 4096 float4, coalesced; quantize+pack 4
      int c = i * 256 + tid;
      int t = c >> 5;
      int e4 = c & 31;
      float4 v = src[c];
      unsigned w = q8u(v.x) | (q8u(v.y) << 8) | (q8u(v.z) << 16) | (q8u(v.w) << 24);
      *reinterpret_cast<unsigned*>(&s8[t * 144 + e4 * 4]) = w;
    }
    __syncthreads();
    uint4* dst = reinterpret_cast<uint4*>(docA8 + d * 16384);
    #pragma unroll
    for (int i = 0; i < 4; ++i) {            // 1024 fragment chunks, coalesced out
      int cc = i * 256 + tid;
      int mt = cc >> 8;
      int ks = (cc >> 6) & 3;
      int lo = cc & 63;
      int t  = mt * 32 + (lo & 31);
      int e0 = ks * 32 + (lo >> 5) * 16;
      dst[cc] = *reinterpret_cast<const uint4*>(&s8[t * 144 + e0]);  // 4-way bank, one-off
    }
    return;
  }
  const int q = blockIdx.x - 128;
  __shared__ float sq[EE * (LQ + 1)];        // 16.9 KB, pad 33 breaks banks
  const float* src = qry + q * EE * LQ;
  #pragma unroll
  for (int i = 0; i < 4; ++i) {              // 1024 float4 of [E][L], coalesced
    int c = i * 256 + tid;
    int e = c >> 3;
    int l = (c & 7) << 2;
    float4 v = reinterpret_cast<const float4*>(src)[c];
    sq[e * 33 + l + 0] = v.x;
    sq[e * 33 + l + 1] = v.y;
    sq[e * 33 + l + 2] = v.z;
    sq[e * 33 + l + 3] = v.w;
  }
  __syncthreads();
  uint4* dst = reinterpret_cast<uint4*>(qB8 + q * 4096);
  {
    int cc = tid;                            // exactly 256 chunks
    int ks = cc >> 6;
    int lo = cc & 63;
    int l  = lo & 31;
    int e0 = ks * 32 + (lo >> 5) * 16;
    unsigned w[4];
    #pragma unroll
    for (int dw = 0; dw < 4; ++dw)
      w[dw] = q8u(sq[(e0 + dw * 4 + 0) * 33 + l])
            | (q8u(sq[(e0 + dw * 4 + 1) * 33 + l]) << 8)
            | (q8u(sq[(e0 + dw * 4 + 2) * 33 + l]) << 16)
            | (q8u(sq[(e0 + dw * 4 + 3) * 33 + l]) << 24);
    uint4 o; o.x = w[0]; o.y = w[1]; o.z = w[2]; o.w = w[3];
    dst[cc] = o;
  }
}

// ---- Kernel 2: maxsim i8, FULL doc per wave, zero LDS, zero barriers.
// R12 structure at half the bytes and 2x the MFMA rate: wave holds doc d in
// A-frags (64 VGPRs, i8) + owns 8 distinct queries processed singly (b 16 +
// acc 16 regs) -> demand ~115, aiming <=128 for 4 waves/SIMD. NO min-waves
// forcing (R2/R7 spill lesson). Per query: 16 mfma_i32_32x32x32_i8 (4 mt x
// 4 ks chains); max over doc tokens in i32 (order-preserving), scale by
// 1/127^2 only at the final col-sum. Grid (128 d, 4 qg) = 512 blocks. ----
__global__ __launch_bounds__(256)
void maxsim_kernel(const unsigned char* __restrict__ docA8,
                   const unsigned char* __restrict__ qB8,
                   float* __restrict__ out) {
  const int d    = blockIdx.x;
  const int qg   = blockIdx.y;
  const int tid  = threadIdx.x;
  const int wave = tid >> 6;
  const int lane = tid & 63;
  const int q0   = qg * 32 + wave * 8;     // this wave's 8 queries

  // A-frags: whole doc, 16 coalesced b128 loads (64 VGPRs), held permanently.
  const int4v* As = reinterpret_cast<const int4v*>(docA8) + d * 1024 + lane;
  int4v afrag[4][4];
  #pragma unroll
  for (int mt = 0; mt < 4; ++mt)
    #pragma unroll
    for (int ks = 0; ks < 4; ++ks)
      afrag[mt][ks] = As[(mt * 4 + ks) * 64];

  const int4v* Bs = reinterpret_cast<const int4v*>(qB8) + q0 * 256 + lane;

  #pragma unroll 1
  for (int p = 0; p < 8; ++p) {
    // B-frags for this query: 4 coalesced b128 loads (16 VGPRs, reused).
    const int4v* Bp = Bs + p * 256;
    int4v b[4];
    #pragma unroll
    for (int ks = 0; ks < 4; ++ks) b[ks] = Bp[ks * 64];

    int cm = (int)0x80000000;
    #pragma unroll
    for (int mt = 0; mt < 4; ++mt) {
      i32x16 acc = {0, 0, 0, 0, 0, 0, 0, 0, 0, 0, 0, 0, 0, 0, 0, 0};
      #pragma unroll
      for (int ks = 0; ks < 4; ++ks)
        acc = __builtin_amdgcn_mfma_i32_32x32x32_i8(afrag[mt][ks], b[ks], acc, 0, 0, 0);
      // Fold 16 acc rows (r=(reg&3)+8*(reg>>2)+4*kh; C/D layout is
      // dtype-independent) into the running per-column max.
      int m = imax(imax(imax(imax(acc[0], acc[1]),  imax(acc[2], acc[3])),
                        imax(imax(acc[4], acc[5]),  imax(acc[6], acc[7]))),
                   imax(imax(imax(acc[8], acc[9]),  imax(acc[10], acc[11])),
                        imax(imax(acc[12], acc[13]), imax(acc[14], acc[15]))));
      cm = imax(cm, m);
    }
    // xor32 merges kh halves -> max over all 128 doc tokens for col lane&31;
    // scale once, sum the 32 cols, lane 0 stores.
    cm = imax(cm, __shfl_xor(cm, 32, 64));
    float f = (float)cm * (1.0f / 16129.0f);
    f += __shfl_xor(f, 1, 64);
    f += __shfl_xor(f, 2, 64);
    f += __shfl_xor(f, 4, 64);
    f += __shfl_xor(f, 8, 64);
    f += __shfl_xor(f, 16, 64);
    if (lane == 0) out[(q0 + p) * ND + d] = f;
  }
}

extern "C" void kernel_launch(void* const* d_in, const int* in_sizes, int n_in,
                              void* d_out, int out_size, void* d_ws, size_t ws_size,
                              hipStream_t stream) {
  const float* doc = (const float*)d_in[0];   // [128,128,128] fp32
  const float* qry = (const float*)d_in[1];   // [128,128,32]  fp32
  float* out = (float*)d_out;                 // [128,128]     fp32

  unsigned char* docA8 = (unsigned char*)d_ws;             // 2 MiB, frag-ordered i8
  unsigned char* qB8   = docA8 + ND * LD * EE;             // 512 KiB, frag-ordered i8

  convert_kernel<<<dim3(256), dim3(256), 0, stream>>>(doc, qry, docA8, qB8);
  maxsim_kernel<<<dim3(ND, NQ / 32), dim3(256), 0, stream>>>(docA8, qB8, out);
}

// Round 14
// 70.195 us; speedup vs baseline: 1.2572x; 1.0058x over previous
//
#include <hip/hip_runtime.h>
#include <hip/hip_bf16.h>

typedef int int4v  __attribute__((ext_vector_type(4)));
typedef int i32x16 __attribute__((ext_vector_type(16)));

#define ND 128
#define LD 128
#define EE 128
#define NQ 128
#define LQ 32

__device__ __forceinline__ unsigned q8u(float x) {
  float v = __builtin_rintf(x * 127.0f);          // inputs are L2-normalized: |x|<=1
  v = fminf(127.0f, fmaxf(-127.0f, v));
  return ((int)v) & 0xff;
}
__device__ __forceinline__ int imax(int a, int b) { return a > b ? a : b; }

// ---- Kernel 1: convert fp32 -> fragment-ordered i8 (fixed scale 127). (R13, proven)
// blocks [0,128): doc d -> docA8. Chunk ((d*4+mt)*4+ks)*64+lane (16B) holds
//   i8(doc[d][mt*32+(lane&31)][ks*32+(lane>>5)*16 + 0..15])   (A-frag, K=32)
// blocks [128,256): query q -> qB8. Chunk (q*4+ks)*64+lane holds
//   i8(qry[q][ks*32+(lane>>5)*16 + 0..15][lane&31])           (B-frag, K=32)
__global__ __launch_bounds__(256)
void convert_kernel(const float* __restrict__ doc, const float* __restrict__ qry,
                    unsigned char* __restrict__ docA8, unsigned char* __restrict__ qB8) {
  const int tid = threadIdx.x;
  if (blockIdx.x < 128) {
    const int d = blockIdx.x;
    __shared__ unsigned char s8[LD * 144];   // 18 KB; row stride 144B = 9*16
    const float4* src = reinterpret_cast<const float4*>(doc + d * LD * EE);
    #pragma unroll
    for (int i = 0; i < 16; ++i) {           // 4096 float4, coalesced; quantize+pack 4
      int c = i * 256 + tid;
      int t = c >> 5;
      int e4 = c & 31;
      float4 v = src[c];
      unsigned w = q8u(v.x) | (q8u(v.y) << 8) | (q8u(v.z) << 16) | (q8u(v.w) << 24);
      *reinterpret_cast<unsigned*>(&s8[t * 144 + e4 * 4]) = w;
    }
    __syncthreads();
    uint4* dst = reinterpret_cast<uint4*>(docA8 + d * 16384);
    #pragma unroll
    for (int i = 0; i < 4; ++i) {            // 1024 fragment chunks, coalesced out
      int cc = i * 256 + tid;
      int mt = cc >> 8;
      int ks = (cc >> 6) & 3;
      int lo = cc & 63;
      int t  = mt * 32 + (lo & 31);
      int e0 = ks * 32 + (lo >> 5) * 16;
      dst[cc] = *reinterpret_cast<const uint4*>(&s8[t * 144 + e0]);
    }
    return;
  }
  const int q = blockIdx.x - 128;
  __shared__ float sq[EE * (LQ + 1)];        // 16.9 KB, pad 33 breaks banks
  const float* src = qry + q * EE * LQ;
  #pragma unroll
  for (int i = 0; i < 4; ++i) {              // 1024 float4 of [E][L], coalesced
    int c = i * 256 + tid;
    int e = c >> 3;
    int l = (c & 7) << 2;
    float4 v = reinterpret_cast<const float4*>(src)[c];
    sq[e * 33 + l + 0] = v.x;
    sq[e * 33 + l + 1] = v.y;
    sq[e * 33 + l + 2] = v.z;
    sq[e * 33 + l + 3] = v.w;
  }
  __syncthreads();
  uint4* dst = reinterpret_cast<uint4*>(qB8 + q * 4096);
  {
    int cc = tid;                            // exactly 256 chunks
    int ks = cc >> 6;
    int lo = cc & 63;
    int l  = lo & 31;
    int e0 = ks * 32 + (lo >> 5) * 16;
    unsigned w[4];
    #pragma unroll
    for (int dw = 0; dw < 4; ++dw)
      w[dw] = q8u(sq[(e0 + dw * 4 + 0) * 33 + l])
            | (q8u(sq[(e0 + dw * 4 + 1) * 33 + l]) << 8)
            | (q8u(sq[(e0 + dw * 4 + 2) * 33 + l]) << 16)
            | (q8u(sq[(e0 + dw * 4 + 3) * 33 + l]) << 24);
    uint4 o; o.x = w[0]; o.y = w[1]; o.z = w[2]; o.w = w[3];
    dst[cc] = o;
  }
}

// ---- Kernel 2: maxsim i8, FULL doc per wave, zero LDS, zero barriers.
// R13 + dual-query interleaved MFMA chains (R12's dep-hiding trick): per pass
// 2 queries, 8 independent mfma_i32_32x32x32_i8 alternating acc0/acc1 per
// 2 m-tiles. Regs ~140: fine — occupancy is GRID-limited at 2 blocks/CU
// (8 waves/CU), VGPR cap for 2 waves/SIMD is ~256. NO min-waves forcing
// (R2/R7 spill lesson). Max over doc tokens in i32 (order-preserving);
// scale 1/127^2 at the final col-sum only. Grid (128 d, 4 qg) = 512. ----
__global__ __launch_bounds__(256)
void maxsim_kernel(const unsigned char* __restrict__ docA8,
                   const unsigned char* __restrict__ qB8,
                   float* __restrict__ out) {
  const int d    = blockIdx.x;
  const int qg   = blockIdx.y;
  const int tid  = threadIdx.x;
  const int wave = tid >> 6;
  const int lane = tid & 63;
  const int q0   = qg * 32 + wave * 8;     // this wave's 8 queries

  // A-frags: whole doc, 16 coalesced b128 loads (64 VGPRs), held permanently.
  const int4v* As = reinterpret_cast<const int4v*>(docA8) + d * 1024 + lane;
  int4v afrag[4][4];
  #pragma unroll
  for (int mt = 0; mt < 4; ++mt)
    #pragma unroll
    for (int ks = 0; ks < 4; ++ks)
      afrag[mt][ks] = As[(mt * 4 + ks) * 64];

  const int4v* Bs = reinterpret_cast<const int4v*>(qB8) + q0 * 256 + lane;

  #pragma unroll 1
  for (int p = 0; p < 4; ++p) {
    // B-frags for this query pair: 8 coalesced b128 loads (32 VGPRs, reused).
    const int4v* Bp = Bs + p * 512;
    int4v b0[4], b1[4];
    #pragma unroll
    for (int ks = 0; ks < 4; ++ks) {
      b0[ks] = Bp[ks * 64];
      b1[ks] = Bp[256 + ks * 64];
    }

    int cm0 = (int)0x80000000, cm1 = (int)0x80000000;
    #pragma unroll
    for (int mt = 0; mt < 4; ++mt) {
      i32x16 acc0 = {0, 0, 0, 0, 0, 0, 0, 0, 0, 0, 0, 0, 0, 0, 0, 0};
      i32x16 acc1 = acc0;
      #pragma unroll
      for (int ks = 0; ks < 4; ++ks) {     // 2 interleaved dep chains
        acc0 = __builtin_amdgcn_mfma_i32_32x32x32_i8(afrag[mt][ks], b0[ks], acc0, 0, 0, 0);
        acc1 = __builtin_amdgcn_mfma_i32_32x32x32_i8(afrag[mt][ks], b1[ks], acc1, 0, 0, 0);
      }
      // Fold 16 acc rows (r=(reg&3)+8*(reg>>2)+4*kh; C/D layout is
      // dtype-independent) into the running per-column maxes.
      int m0 = imax(imax(imax(imax(acc0[0], acc0[1]),  imax(acc0[2], acc0[3])),
                         imax(imax(acc0[4], acc0[5]),  imax(acc0[6], acc0[7]))),
                    imax(imax(imax(acc0[8], acc0[9]),  imax(acc0[10], acc0[11])),
                         imax(imax(acc0[12], acc0[13]), imax(acc0[14], acc0[15]))));
      cm0 = imax(cm0, m0);
      int m1 = imax(imax(imax(imax(acc1[0], acc1[1]),  imax(acc1[2], acc1[3])),
                         imax(imax(acc1[4], acc1[5]),  imax(acc1[6], acc1[7]))),
                    imax(imax(imax(acc1[8], acc1[9]),  imax(acc1[10], acc1[11])),
                         imax(imax(acc1[12], acc1[13]), imax(acc1[14], acc1[15]))));
      cm1 = imax(cm1, m1);
    }
    // xor32 merges kh halves -> max over all 128 doc tokens for col lane&31;
    // scale once, sum the 32 cols, lane 0 stores both queries.
    cm0 = imax(cm0, __shfl_xor(cm0, 32, 64));
    cm1 = imax(cm1, __shfl_xor(cm1, 32, 64));
    float f0 = (float)cm0 * (1.0f / 16129.0f);
    float f1 = (float)cm1 * (1.0f / 16129.0f);
    f0 += __shfl_xor(f0, 1, 64);
    f0 += __shfl_xor(f0, 2, 64);
    f0 += __shfl_xor(f0, 4, 64);
    f0 += __shfl_xor(f0, 8, 64);
    f0 += __shfl_xor(f0, 16, 64);
    f1 += __shfl_xor(f1, 1, 64);
    f1 += __shfl_xor(f1, 2, 64);
    f1 += __shfl_xor(f1, 4, 64);
    f1 += __shfl_xor(f1, 8, 64);
    f1 += __shfl_xor(f1, 16, 64);
    if (lane == 0) {
      out[(q0 + 2 * p) * ND + d]     = f0;
      out[(q0 + 2 * p + 1) * ND + d] = f1;
    }
  }
}

extern "C" void kernel_launch(void* const* d_in, const int* in_sizes, int n_in,
                              void* d_out, int out_size, void* d_ws, size_t ws_size,
                              hipStream_t stream) {
  const float* doc = (const float*)d_in[0];   // [128,128,128] fp32
  const float* qry = (const float*)d_in[1];   // [128,128,32]  fp32
  float* out = (float*)d_out;                 // [128,128]     fp32

  unsigned char* docA8 = (unsigned char*)d_ws;             // 2 MiB, frag-ordered i8
  unsigned char* qB8   = docA8 + ND * LD * EE;             // 512 KiB, frag-ordered i8

  convert_kernel<<<dim3(256), dim3(256), 0, stream>>>(doc, qry, docA8, qB8);
  maxsim_kernel<<<dim3(ND, NQ / 32), dim3(256), 0, stream>>>(docA8, qB8, out);
}